// Round 2
// baseline (581.532 us; speedup 1.0000x reference)
//
#include <hip/hip_runtime.h>
#include <hip/hip_bf16.h>

// ManifoldHyperConnections: T=4096 rows, K=16384, 24 output cols + sumsq,
// then per-row 4x4 Sinkhorn (400 iters).
//
// R1: LDS-staged GEMV. Workgroup (256 thr = 4 waves) owns 64 rows x 1024 k.
// Staging: lanes-across-k coalesced global float4 loads -> LDS tile
// (64 rows x 64 k, stride 65 to break bank aliasing). Compute: lane=row,
// k wave-uniform -> weight rows are SCALAR loads (zero per-lane w traffic),
// 25 FMAs per element. Split-K (16 chunks) combined via fp32 atomicAdd.

#define TROWS 4096
#define KDIM  16384
#define NOUT  24
#define KC    16                 // split-K chunks
#define KPER  (KDIM / KC)        // 1024 k per workgroup
#define TILEK 64                 // k per LDS tile
#define NTILE (KPER / TILEK)     // 16 tiles
#define LDS_STRIDE 65            // 64 + 1 pad -> bank = (row+k)%32, 2-way (free)

__device__ __forceinline__ float fast_rcp(float x) {
    return __builtin_amdgcn_rcpf(x);
}
__device__ __forceinline__ float fast_rsqrt(float x) {
    return __builtin_amdgcn_rsqf(x);
}

__global__ __launch_bounds__(256) void gemv_part(const float* __restrict__ x,
                                                 const float* __restrict__ w,
                                                 float* __restrict__ hacc) {
    __shared__ float xs[64 * LDS_STRIDE];

    const int bid  = blockIdx.x;
    const int rg   = bid & 63;        // row group (64 rows)
    const int kc   = bid >> 6;        // split-K chunk
    const int k0   = kc * KPER;

    const int tid  = threadIdx.x;
    const int wv   = tid >> 6;        // wave 0..3
    const int lane = tid & 63;        // compute phase: lane = row

    // staging map: thread covers rows {sr, sr+16, sr+32, sr+48}, 1 float4 each
    const int sr  = tid >> 4;         // 0..15 base row
    const int sk4 = tid & 15;         // float4 index within tile row

    float acc[NOUT + 1];
#pragma unroll
    for (int j = 0; j <= NOUT; ++j) acc[j] = 0.0f;

    const float* xg = x + (size_t)rg * 64 * KDIM + k0;

#pragma unroll 1
    for (int t = 0; t < NTILE; ++t) {
        const int kt = t * TILEK;
        __syncthreads();
        // ---- stage 64 rows x 64 k into LDS (coalesced 256B segments) ----
#pragma unroll
        for (int r4 = 0; r4 < 4; ++r4) {
            const int row = r4 * 16 + sr;
            const float4 v = *(const float4*)(xg + (size_t)row * KDIM + kt + sk4 * 4);
            float* d = xs + row * LDS_STRIDE + sk4 * 4;
            d[0] = v.x; d[1] = v.y; d[2] = v.z; d[3] = v.w;
        }
        __syncthreads();
        // ---- compute: wave wv handles k = kt + wv*16 .. +15, lane = row ----
        const float* wk = w + (size_t)(k0 + kt + wv * 16) * NOUT;  // wave-uniform
        const float* xk = xs + lane * LDS_STRIDE + wv * 16;
#pragma unroll
        for (int u = 0; u < 16; ++u) {
            const float xe = xk[u];
            const float* wr = wk + u * NOUT;                        // scalar loads
            acc[NOUT] = fmaf(xe, xe, acc[NOUT]);
#pragma unroll
            for (int j = 0; j < NOUT; ++j) acc[j] = fmaf(wr[j], xe, acc[j]);
        }
    }

    // combine split-K partials; hacc[j][row] layout (coalesced across lanes)
    const int row = rg * 64 + lane;
#pragma unroll
    for (int j = 0; j <= NOUT; ++j)
        atomicAdd(hacc + (size_t)j * TROWS + row, acc[j]);
}

__global__ __launch_bounds__(64) void sinkhorn_epilogue(const float* __restrict__ hacc,
                                                        const float* __restrict__ bias,
                                                        const float* __restrict__ alpha,
                                                        float* __restrict__ out) {
    const int row = blockIdx.x * 64 + threadIdx.x;

    float h[25];
#pragma unroll
    for (int j = 0; j < 25; ++j) h[j] = hacc[(size_t)j * TROWS + row];

    const float r_inv = fast_rsqrt(h[24] * (1.0f / (float)KDIM));
    const float a0 = alpha[0], a1 = alpha[1], a2 = alpha[2];

#pragma unroll
    for (int i = 0; i < 4; ++i) {
        const float zpre = fmaf(r_inv * a0, h[i], bias[i]);
        out[(size_t)row * 4 + i] = fast_rcp(1.0f + __expf(-zpre));
        const float zpo = fmaf(r_inv * a1, h[4 + i], bias[4 + i]);
        out[(size_t)16384 + (size_t)row * 4 + i] = 2.0f * fast_rcp(1.0f + __expf(-zpo));
    }

    float E[16];
#pragma unroll
    for (int t = 0; t < 16; ++t)
        E[t] = __expf(fmaf(r_inv * a2, h[8 + t], bias[8 + t]));

    float u0 = 1.0f, u1 = 1.0f, u2 = 1.0f, u3 = 1.0f;
    float v0 = 1.0f, v1 = 1.0f, v2 = 1.0f, v3 = 1.0f;

#pragma unroll 1
    for (int it = 0; it < 400; ++it) {
        float s0 = fmaf(E[0],  v0, fmaf(E[1],  v1, fmaf(E[2],  v2, E[3]  * v3)));
        float s1 = fmaf(E[4],  v0, fmaf(E[5],  v1, fmaf(E[6],  v2, E[7]  * v3)));
        float s2 = fmaf(E[8],  v0, fmaf(E[9],  v1, fmaf(E[10], v2, E[11] * v3)));
        float s3 = fmaf(E[12], v0, fmaf(E[13], v1, fmaf(E[14], v2, E[15] * v3)));
        u0 = fast_rcp(s0 + 1e-12f);
        u1 = fast_rcp(s1 + 1e-12f);
        u2 = fast_rcp(s2 + 1e-12f);
        u3 = fast_rcp(s3 + 1e-12f);
        float t0 = fmaf(E[0], u0, fmaf(E[4], u1, fmaf(E[8],  u2, E[12] * u3)));
        float t1 = fmaf(E[1], u0, fmaf(E[5], u1, fmaf(E[9],  u2, E[13] * u3)));
        float t2 = fmaf(E[2], u0, fmaf(E[6], u1, fmaf(E[10], u2, E[14] * u3)));
        float t3 = fmaf(E[3], u0, fmaf(E[7], u1, fmaf(E[11], u2, E[15] * u3)));
        v0 = fast_rcp(t0 + 1e-12f);
        v1 = fast_rcp(t1 + 1e-12f);
        v2 = fast_rcp(t2 + 1e-12f);
        v3 = fast_rcp(t3 + 1e-12f);
    }

    const size_t ob = 32768 + (size_t)row * 16;
    out[ob + 0]  = u0 * E[0]  * v0;
    out[ob + 1]  = u0 * E[1]  * v1;
    out[ob + 2]  = u0 * E[2]  * v2;
    out[ob + 3]  = u0 * E[3]  * v3;
    out[ob + 4]  = u1 * E[4]  * v0;
    out[ob + 5]  = u1 * E[5]  * v1;
    out[ob + 6]  = u1 * E[6]  * v2;
    out[ob + 7]  = u1 * E[7]  * v3;
    out[ob + 8]  = u2 * E[8]  * v0;
    out[ob + 9]  = u2 * E[9]  * v1;
    out[ob + 10] = u2 * E[10] * v2;
    out[ob + 11] = u2 * E[11] * v3;
    out[ob + 12] = u3 * E[12] * v0;
    out[ob + 13] = u3 * E[13] * v1;
    out[ob + 14] = u3 * E[14] * v2;
    out[ob + 15] = u3 * E[15] * v3;
}

extern "C" void kernel_launch(void* const* d_in, const int* in_sizes, int n_in,
                              void* d_out, int out_size, void* d_ws, size_t ws_size,
                              hipStream_t stream) {
    const float* x     = (const float*)d_in[0];
    const float* w     = (const float*)d_in[1];
    const float* bias  = (const float*)d_in[2];
    const float* alpha = (const float*)d_in[3];
    float* out  = (float*)d_out;
    float* hacc = (float*)d_ws;   // 25 * 4096 floats = 400 KB

    hipMemsetAsync(hacc, 0, (size_t)(NOUT + 1) * TROWS * sizeof(float), stream);
    gemv_part<<<dim3(64 * KC), dim3(256), 0, stream>>>(x, w, hacc);
    sinkhorn_epilogue<<<dim3(TROWS / 64), dim3(64), 0, stream>>>(hacc, bias, alpha, out);
}

// Round 3
// 457.681 us; speedup vs baseline: 1.2706x; 1.2706x over previous
//
#include <hip/hip_runtime.h>
#include <hip/hip_bf16.h>

// ManifoldHyperConnections: T=4096 rows, K=16384, 24 output cols + sumsq,
// then per-row 4x4 Sinkhorn (400 iters).
//
// R2: the R0/R1 inner loop was latency-bound on per-lane VMEM loads of w
// (SGPR_Count=32 proved the hoped-for s_loads never materialized; VALU 8%,
// HBM 7% => stall-bound). Fix: stage w into LDS once per tile and read it
// with same-address ds_read_b128 broadcasts (no vmcnt chain); amortize each
// broadcast over 2 rows/lane (50 accumulators). x tile stored transposed
// [k][row] stride 129: compute reads lane-consecutive (2-way, free),
// staging writes spread over banks. Expect HBM-bound ~50-70 us.

#define TROWS 4096
#define KDIM  16384
#define NOUT  24
#define RG    128                 // rows per workgroup (2 per lane)
#define KC    32                  // split-K chunks
#define KPER  (KDIM / KC)         // 512 k per workgroup
#define TILEK 64                  // k per LDS tile
#define NTILE (KPER / TILEK)      // 8 tiles
#define XSTR  (RG + 1)            // 129: bank = lane%32 on compute reads

__device__ __forceinline__ float fast_rcp(float x)   { return __builtin_amdgcn_rcpf(x); }
__device__ __forceinline__ float fast_rsqrt(float x) { return __builtin_amdgcn_rsqf(x); }

__global__ __launch_bounds__(256) void gemv_part(const float* __restrict__ x,
                                                 const float* __restrict__ w,
                                                 float* __restrict__ hacc) {
    __shared__ float xT[TILEK * XSTR];   // [k][row], 33 KB
    __shared__ float wt[TILEK * NOUT];   // [k][j],   6 KB

    const int bid  = blockIdx.x;
    const int rb   = bid & 31;        // row block 0..31
    const int kc   = bid >> 5;        // split-K chunk 0..31
    const int rg0  = rb * RG;
    const int k0   = kc * KPER;

    const int t    = threadIdx.x;
    const int wv   = t >> 6;          // wave 0..3 -> k slice
    const int lane = t & 63;

    const int srow = t >> 4;          // staging: base row 0..15
    const int sf4  = t & 15;          // staging: float4 index 0..15

    float accA[NOUT + 1], accB[NOUT + 1];
#pragma unroll
    for (int j = 0; j <= NOUT; ++j) { accA[j] = 0.0f; accB[j] = 0.0f; }

#pragma unroll 1
    for (int tile = 0; tile < NTILE; ++tile) {
        const int kt = k0 + tile * TILEK;
        __syncthreads();
        // ---- stage x: 128 rows x 64 k, transposed into xT[k][row] ----
        const float* xg = x + (size_t)rg0 * KDIM + kt;
        const int kk = sf4 * 4;
#pragma unroll
        for (int s = 0; s < 8; ++s) {
            const int row = srow + 16 * s;
            const float4 v = *(const float4*)(xg + (size_t)row * KDIM + kk);
            xT[(kk + 0) * XSTR + row] = v.x;
            xT[(kk + 1) * XSTR + row] = v.y;
            xT[(kk + 2) * XSTR + row] = v.z;
            xT[(kk + 3) * XSTR + row] = v.w;
        }
        // ---- stage w: 64 k x 24 = 384 float4 ----
        const float4* wg4 = (const float4*)(w + (size_t)kt * NOUT);
        ((float4*)wt)[t] = wg4[t];
        if (t < 128) ((float4*)wt)[256 + t] = wg4[256 + t];
        __syncthreads();
        // ---- compute: wave wv -> k-local wv*16 + u; lane holds 2 rows ----
        const float* xk = xT + (wv * 16) * XSTR;
        const float* wk = wt + (wv * 16) * NOUT;
#pragma unroll
        for (int u = 0; u < 16; ++u) {
            const float xa = xk[u * XSTR + lane];
            const float xb = xk[u * XSTR + 64 + lane];
            const float4* wr = (const float4*)(wk + u * NOUT);  // uniform addr -> broadcast
            float wbuf[24];
            *(float4*)(wbuf +  0) = wr[0];
            *(float4*)(wbuf +  4) = wr[1];
            *(float4*)(wbuf +  8) = wr[2];
            *(float4*)(wbuf + 12) = wr[3];
            *(float4*)(wbuf + 16) = wr[4];
            *(float4*)(wbuf + 20) = wr[5];
            accA[NOUT] = fmaf(xa, xa, accA[NOUT]);
            accB[NOUT] = fmaf(xb, xb, accB[NOUT]);
#pragma unroll
            for (int j = 0; j < NOUT; ++j) {
                accA[j] = fmaf(wbuf[j], xa, accA[j]);
                accB[j] = fmaf(wbuf[j], xb, accB[j]);
            }
        }
    }

    // combine split-K partials; hacc[j][row], lanes write consecutive addrs
#pragma unroll
    for (int j = 0; j <= NOUT; ++j) {
        atomicAdd(hacc + (size_t)j * TROWS + rg0 + lane,      accA[j]);
        atomicAdd(hacc + (size_t)j * TROWS + rg0 + 64 + lane, accB[j]);
    }
}

__global__ __launch_bounds__(64) void sinkhorn_epilogue(const float* __restrict__ hacc,
                                                        const float* __restrict__ bias,
                                                        const float* __restrict__ alpha,
                                                        float* __restrict__ out) {
    const int row = blockIdx.x * 64 + threadIdx.x;

    float h[25];
#pragma unroll
    for (int j = 0; j < 25; ++j) h[j] = hacc[(size_t)j * TROWS + row];

    const float r_inv = fast_rsqrt(h[24] * (1.0f / (float)KDIM));
    const float a0 = alpha[0], a1 = alpha[1], a2 = alpha[2];

#pragma unroll
    for (int i = 0; i < 4; ++i) {
        const float zpre = fmaf(r_inv * a0, h[i], bias[i]);
        out[(size_t)row * 4 + i] = fast_rcp(1.0f + __expf(-zpre));
        const float zpo = fmaf(r_inv * a1, h[4 + i], bias[4 + i]);
        out[(size_t)16384 + (size_t)row * 4 + i] = 2.0f * fast_rcp(1.0f + __expf(-zpo));
    }

    float E[16];
#pragma unroll
    for (int t = 0; t < 16; ++t)
        E[t] = __expf(fmaf(r_inv * a2, h[8 + t], bias[8 + t]));

    float u0 = 1.0f, u1 = 1.0f, u2 = 1.0f, u3 = 1.0f;
    float v0 = 1.0f, v1 = 1.0f, v2 = 1.0f, v3 = 1.0f;

#pragma unroll 1
    for (int it = 0; it < 400; ++it) {
        float s0 = fmaf(E[0],  v0, fmaf(E[1],  v1, fmaf(E[2],  v2, E[3]  * v3)));
        float s1 = fmaf(E[4],  v0, fmaf(E[5],  v1, fmaf(E[6],  v2, E[7]  * v3)));
        float s2 = fmaf(E[8],  v0, fmaf(E[9],  v1, fmaf(E[10], v2, E[11] * v3)));
        float s3 = fmaf(E[12], v0, fmaf(E[13], v1, fmaf(E[14], v2, E[15] * v3)));
        u0 = fast_rcp(s0 + 1e-12f);
        u1 = fast_rcp(s1 + 1e-12f);
        u2 = fast_rcp(s2 + 1e-12f);
        u3 = fast_rcp(s3 + 1e-12f);
        float t0 = fmaf(E[0], u0, fmaf(E[4], u1, fmaf(E[8],  u2, E[12] * u3)));
        float t1 = fmaf(E[1], u0, fmaf(E[5], u1, fmaf(E[9],  u2, E[13] * u3)));
        float t2 = fmaf(E[2], u0, fmaf(E[6], u1, fmaf(E[10], u2, E[14] * u3)));
        float t3 = fmaf(E[3], u0, fmaf(E[7], u1, fmaf(E[11], u2, E[15] * u3)));
        v0 = fast_rcp(t0 + 1e-12f);
        v1 = fast_rcp(t1 + 1e-12f);
        v2 = fast_rcp(t2 + 1e-12f);
        v3 = fast_rcp(t3 + 1e-12f);
    }

    const size_t ob = 32768 + (size_t)row * 16;
    out[ob + 0]  = u0 * E[0]  * v0;
    out[ob + 1]  = u0 * E[1]  * v1;
    out[ob + 2]  = u0 * E[2]  * v2;
    out[ob + 3]  = u0 * E[3]  * v3;
    out[ob + 4]  = u1 * E[4]  * v0;
    out[ob + 5]  = u1 * E[5]  * v1;
    out[ob + 6]  = u1 * E[6]  * v2;
    out[ob + 7]  = u1 * E[7]  * v3;
    out[ob + 8]  = u2 * E[8]  * v0;
    out[ob + 9]  = u2 * E[9]  * v1;
    out[ob + 10] = u2 * E[10] * v2;
    out[ob + 11] = u2 * E[11] * v3;
    out[ob + 12] = u3 * E[12] * v0;
    out[ob + 13] = u3 * E[13] * v1;
    out[ob + 14] = u3 * E[14] * v2;
    out[ob + 15] = u3 * E[15] * v3;
}

extern "C" void kernel_launch(void* const* d_in, const int* in_sizes, int n_in,
                              void* d_out, int out_size, void* d_ws, size_t ws_size,
                              hipStream_t stream) {
    const float* x     = (const float*)d_in[0];
    const float* w     = (const float*)d_in[1];
    const float* bias  = (const float*)d_in[2];
    const float* alpha = (const float*)d_in[3];
    float* out  = (float*)d_out;
    float* hacc = (float*)d_ws;   // 25 * 4096 floats = 400 KB

    hipMemsetAsync(hacc, 0, (size_t)(NOUT + 1) * TROWS * sizeof(float), stream);
    gemv_part<<<dim3(32 * KC), dim3(256), 0, stream>>>(x, w, hacc);
    sinkhorn_epilogue<<<dim3(TROWS / 64), dim3(64), 0, stream>>>(hacc, bias, alpha, out);
}

// Round 4
// 445.758 us; speedup vs baseline: 1.3046x; 1.0267x over previous
//
#include <hip/hip_runtime.h>
#include <hip/hip_bf16.h>

// ManifoldHyperConnections: T=4096 rows, K=16384, 24 output cols + sumsq,
// then per-row 4x4 Sinkhorn (400 iters).
//
// R4: tile-level software pipeline. R3 counters (VALU 15.7%, HBM 15%, all
// pipes idle) => phase serialization: global-load drain at the barrier, then
// compute with no VMEM in flight. Now: prefetch tile t+1 into VGPRs DURING
// compute of tile t; barrier only separates LDS write from LDS read. Keeps
// ~32KB/block of loads in flight continuously -> HBM-bound.
// w stays in LDS (same-address ds_read_b128 broadcasts); x transposed
// [k][row] stride 129 (2-way bank aliasing = free).

#define TROWS 4096
#define KDIM  16384
#define NOUT  24
#define RG    128                 // rows per workgroup (2 per lane)
#define KC    32                  // split-K chunks
#define KPER  (KDIM / KC)         // 512 k per workgroup
#define TILEK 64                  // k per LDS tile
#define NTILE (KPER / TILEK)      // 8 tiles
#define XSTR  (RG + 1)            // 129

__device__ __forceinline__ float fast_rcp(float x)   { return __builtin_amdgcn_rcpf(x); }
__device__ __forceinline__ float fast_rsqrt(float x) { return __builtin_amdgcn_rsqf(x); }

__global__ __launch_bounds__(256) void gemv_part(const float* __restrict__ x,
                                                 const float* __restrict__ w,
                                                 float* __restrict__ hacc) {
    __shared__ float xT[TILEK * XSTR];   // [k][row], 33 KB
    __shared__ float wt[TILEK * NOUT];   // [k][j],   6 KB

    const int bid  = blockIdx.x;
    const int rb   = bid & 31;        // row block 0..31
    const int kc   = bid >> 5;        // split-K chunk 0..31
    const int rg0  = rb * RG;
    const int k0   = kc * KPER;

    const int t    = threadIdx.x;
    const int wv   = t >> 6;          // wave 0..3 -> k slice
    const int lane = t & 63;

    const int srow = t >> 4;          // staging: base row 0..15
    const int sf4  = t & 15;          // staging: float4 index 0..15
    const int kk   = sf4 * 4;

    float accA[NOUT + 1], accB[NOUT + 1];
#pragma unroll
    for (int j = 0; j <= NOUT; ++j) { accA[j] = 0.0f; accB[j] = 0.0f; }

    const float* xg = x + (size_t)rg0 * KDIM + k0;

    // ---- prefetch tile 0 into registers ----
    float4 px[8];
    float4 pw0, pw1;
    {
#pragma unroll
        for (int s = 0; s < 8; ++s)
            px[s] = *(const float4*)(xg + (size_t)(srow + 16 * s) * KDIM + kk);
        const float4* wg4 = (const float4*)(w + (size_t)k0 * NOUT);
        pw0 = wg4[t];
        pw1 = (t < 128) ? wg4[256 + t] : pw0;
    }

#pragma unroll 1
    for (int tile = 0; tile < NTILE; ++tile) {
        __syncthreads();
        // ---- write prefetched tile into LDS (registers -> LDS, no vmcnt) ----
#pragma unroll
        for (int s = 0; s < 8; ++s) {
            const int row = srow + 16 * s;
            xT[(kk + 0) * XSTR + row] = px[s].x;
            xT[(kk + 1) * XSTR + row] = px[s].y;
            xT[(kk + 2) * XSTR + row] = px[s].z;
            xT[(kk + 3) * XSTR + row] = px[s].w;
        }
        ((float4*)wt)[t] = pw0;
        if (t < 128) ((float4*)wt)[256 + t] = pw1;
        __syncthreads();

        // ---- issue prefetch for tile+1 (in flight during compute below) ----
        const int tn = (tile + 1 < NTILE) ? tile + 1 : tile;
        const int ktn = tn * TILEK;
#pragma unroll
        for (int s = 0; s < 8; ++s)
            px[s] = *(const float4*)(xg + (size_t)(srow + 16 * s) * KDIM + ktn + kk);
        {
            const float4* wg4 = (const float4*)(w + (size_t)(k0 + ktn) * NOUT);
            pw0 = wg4[t];
            pw1 = (t < 128) ? wg4[256 + t] : pw0;
        }

        // ---- compute: wave wv -> k-local wv*16 + u; lane holds 2 rows ----
        const float* xk = xT + (wv * 16) * XSTR;
        const float* wk = wt + (wv * 16) * NOUT;
#pragma unroll
        for (int u = 0; u < 16; ++u) {
            const float xa = xk[u * XSTR + lane];
            const float xb = xk[u * XSTR + 64 + lane];
            const float4* wr = (const float4*)(wk + u * NOUT);  // uniform -> broadcast
            float wbuf[24];
            *(float4*)(wbuf +  0) = wr[0];
            *(float4*)(wbuf +  4) = wr[1];
            *(float4*)(wbuf +  8) = wr[2];
            *(float4*)(wbuf + 12) = wr[3];
            *(float4*)(wbuf + 16) = wr[4];
            *(float4*)(wbuf + 20) = wr[5];
            accA[NOUT] = fmaf(xa, xa, accA[NOUT]);
            accB[NOUT] = fmaf(xb, xb, accB[NOUT]);
#pragma unroll
            for (int j = 0; j < NOUT; ++j) {
                accA[j] = fmaf(wbuf[j], xa, accA[j]);
                accB[j] = fmaf(wbuf[j], xb, accB[j]);
            }
        }
    }

    // combine split-K partials; hacc[j][row], lanes write consecutive addrs
#pragma unroll
    for (int j = 0; j <= NOUT; ++j) {
        atomicAdd(hacc + (size_t)j * TROWS + rg0 + lane,      accA[j]);
        atomicAdd(hacc + (size_t)j * TROWS + rg0 + 64 + lane, accB[j]);
    }
}

__global__ __launch_bounds__(64) void sinkhorn_epilogue(const float* __restrict__ hacc,
                                                        const float* __restrict__ bias,
                                                        const float* __restrict__ alpha,
                                                        float* __restrict__ out) {
    const int row = blockIdx.x * 64 + threadIdx.x;

    float h[25];
#pragma unroll
    for (int j = 0; j < 25; ++j) h[j] = hacc[(size_t)j * TROWS + row];

    const float r_inv = fast_rsqrt(h[24] * (1.0f / (float)KDIM));
    const float a0 = alpha[0], a1 = alpha[1], a2 = alpha[2];

#pragma unroll
    for (int i = 0; i < 4; ++i) {
        const float zpre = fmaf(r_inv * a0, h[i], bias[i]);
        out[(size_t)row * 4 + i] = fast_rcp(1.0f + __expf(-zpre));
        const float zpo = fmaf(r_inv * a1, h[4 + i], bias[4 + i]);
        out[(size_t)16384 + (size_t)row * 4 + i] = 2.0f * fast_rcp(1.0f + __expf(-zpo));
    }

    float E[16];
#pragma unroll
    for (int t = 0; t < 16; ++t)
        E[t] = __expf(fmaf(r_inv * a2, h[8 + t], bias[8 + t]));

    float u0 = 1.0f, u1 = 1.0f, u2 = 1.0f, u3 = 1.0f;
    float v0 = 1.0f, v1 = 1.0f, v2 = 1.0f, v3 = 1.0f;

#pragma unroll 1
    for (int it = 0; it < 400; ++it) {
        float s0 = fmaf(E[0],  v0, fmaf(E[1],  v1, fmaf(E[2],  v2, E[3]  * v3)));
        float s1 = fmaf(E[4],  v0, fmaf(E[5],  v1, fmaf(E[6],  v2, E[7]  * v3)));
        float s2 = fmaf(E[8],  v0, fmaf(E[9],  v1, fmaf(E[10], v2, E[11] * v3)));
        float s3 = fmaf(E[12], v0, fmaf(E[13], v1, fmaf(E[14], v2, E[15] * v3)));
        u0 = fast_rcp(s0 + 1e-12f);
        u1 = fast_rcp(s1 + 1e-12f);
        u2 = fast_rcp(s2 + 1e-12f);
        u3 = fast_rcp(s3 + 1e-12f);
        float t0 = fmaf(E[0], u0, fmaf(E[4], u1, fmaf(E[8],  u2, E[12] * u3)));
        float t1 = fmaf(E[1], u0, fmaf(E[5], u1, fmaf(E[9],  u2, E[13] * u3)));
        float t2 = fmaf(E[2], u0, fmaf(E[6], u1, fmaf(E[10], u2, E[14] * u3)));
        float t3 = fmaf(E[3], u0, fmaf(E[7], u1, fmaf(E[11], u2, E[15] * u3)));
        v0 = fast_rcp(t0 + 1e-12f);
        v1 = fast_rcp(t1 + 1e-12f);
        v2 = fast_rcp(t2 + 1e-12f);
        v3 = fast_rcp(t3 + 1e-12f);
    }

    const size_t ob = 32768 + (size_t)row * 16;
    out[ob + 0]  = u0 * E[0]  * v0;
    out[ob + 1]  = u0 * E[1]  * v1;
    out[ob + 2]  = u0 * E[2]  * v2;
    out[ob + 3]  = u0 * E[3]  * v3;
    out[ob + 4]  = u1 * E[4]  * v0;
    out[ob + 5]  = u1 * E[5]  * v1;
    out[ob + 6]  = u1 * E[6]  * v2;
    out[ob + 7]  = u1 * E[7]  * v3;
    out[ob + 8]  = u2 * E[8]  * v0;
    out[ob + 9]  = u2 * E[9]  * v1;
    out[ob + 10] = u2 * E[10] * v2;
    out[ob + 11] = u2 * E[11] * v3;
    out[ob + 12] = u3 * E[12] * v0;
    out[ob + 13] = u3 * E[13] * v1;
    out[ob + 14] = u3 * E[14] * v2;
    out[ob + 15] = u3 * E[15] * v3;
}

extern "C" void kernel_launch(void* const* d_in, const int* in_sizes, int n_in,
                              void* d_out, int out_size, void* d_ws, size_t ws_size,
                              hipStream_t stream) {
    const float* x     = (const float*)d_in[0];
    const float* w     = (const float*)d_in[1];
    const float* bias  = (const float*)d_in[2];
    const float* alpha = (const float*)d_in[3];
    float* out  = (float*)d_out;
    float* hacc = (float*)d_ws;   // 25 * 4096 floats = 400 KB

    hipMemsetAsync(hacc, 0, (size_t)(NOUT + 1) * TROWS * sizeof(float), stream);
    gemv_part<<<dim3(32 * KC), dim3(256), 0, stream>>>(x, w, hacc);
    sinkhorn_epilogue<<<dim3(TROWS / 64), dim3(64), 0, stream>>>(hacc, bias, alpha, out);
}